// Round 1
// baseline (673.581 us; speedup 1.0000x reference)
//
#include <hip/hip_runtime.h>

typedef __bf16 bf16x8 __attribute__((ext_vector_type(8)));
typedef float f32x4 __attribute__((ext_vector_type(4)));
typedef unsigned short u16x8 __attribute__((ext_vector_type(8)));

#define VP 10016  // 10000 padded to multiple of 32 (313 c-steps of 32)

__device__ __forceinline__ unsigned short f2bf(float x){
  unsigned u = __builtin_bit_cast(unsigned, x);
  u += 0x7fffu + ((u>>16)&1u);
  return (unsigned short)(u>>16);
}
__device__ __forceinline__ float bf2f(unsigned short h){
  unsigned u = ((unsigned)h)<<16;
  return __builtin_bit_cast(float, u);
}

// ---------- Wvf: fragment-major W_v  Wvf[vg 640][kk 8][lane 64][8 bf16] ----------
// blocks 160..223 cast W_u -> bf16 (64 blocks x 256 thr x 1 float4 = 65536 floats).
__global__ __launch_bounds__(256) void k_wvf(const float* __restrict__ W_v,
                                             unsigned short* __restrict__ Wvf,
                                             const float* __restrict__ W_u,
                                             unsigned short* __restrict__ Wu_bf){
  if(blockIdx.x >= 160){
    int i = (blockIdx.x-160)*256 + threadIdx.x;   // 0..16383 float4-groups
    const float4 v = *(const float4*)(W_u + (size_t)i*4);
    unsigned a = (unsigned)f2bf(v.x) | ((unsigned)f2bf(v.y)<<16);
    unsigned b = (unsigned)f2bf(v.z) | ((unsigned)f2bf(v.w)<<16);
    *(uint2*)(Wu_bf + (size_t)i*4) = make_uint2(a,b);
    return;
  }
  const int t = threadIdx.x;
  const int w = t>>6, lane = t&63;
  const int l15 = lane&15, sl = lane>>4;
  const int vg = blockIdx.x*4 + w;      // 0..639
  const int v = vg*16 + l15;
  #pragma unroll
  for(int kk=0;kk<8;kk++){
    u16x8 pk = {0,0,0,0,0,0,0,0};
    if(v < 10000){
      const float* p = W_v + (size_t)v*256 + kk*32 + sl*8;
      float4 v0 = *(const float4*)p;
      float4 v1 = *(const float4*)(p+4);
      pk[0]=f2bf(v0.x); pk[1]=f2bf(v0.y); pk[2]=f2bf(v0.z); pk[3]=f2bf(v0.w);
      pk[4]=f2bf(v1.x); pk[5]=f2bf(v1.y); pk[6]=f2bf(v1.z); pk[7]=f2bf(v1.w);
    }
    *(u16x8*)(Wvf + ((size_t)vg*8 + kk)*512 + lane*8) = pk;
  }
}

// ---------- M1f: fragment-major  M1f[ngrp 16][c 313][lane 64][8 bf16] ----------
__global__ __launch_bounds__(256) void k_m1(const float* __restrict__ W_w,
                                            const float* __restrict__ W_emb,
                                            unsigned short* __restrict__ M1f){
  __shared__ float4 ww4[16][75];   // [n][c4] covers e = 4c4..4c4+3  (300 = 75*4)
  const int t = threadIdx.x;
  const int ngrp = blockIdx.y;
  const int n0 = ngrp*16;
  for(int i=t; i<16*75; i+=256){
    int n = i/75, c = i - n*75;
    ww4[n][c] = *(const float4*)(W_w + (size_t)(n0+n)*300 + c*4);
  }
  __syncthreads();
  const int v0 = blockIdx.x*512 + t*2;
  if(v0 >= VP) return;
  const int c  = v0>>5;
  const int sl = (v0>>3)&3;
  const int j  = v0&7;          // even
  unsigned short* outp = M1f + (size_t)(ngrp*313 + c)*512 + sl*128 + j;
  if(v0 >= 10000){
    #pragma unroll
    for(int nn=0;nn<16;nn++) *(unsigned*)&outp[nn*8] = 0u;
    return;
  }
  float acc[16][2];
  #pragma unroll
  for(int nn=0;nn<16;nn++){ acc[nn][0]=0.f; acc[nn][1]=0.f; }
  #pragma unroll 2
  for(int cc=0;cc<75;cc++){
    const float* eb = W_emb + (size_t)(4*cc)*10000 + v0;
    float2 wv0 = *(const float2*)(eb);
    float2 wv1 = *(const float2*)(eb + 10000);
    float2 wv2 = *(const float2*)(eb + 20000);
    float2 wv3 = *(const float2*)(eb + 30000);
    #pragma unroll
    for(int nn=0;nn<16;nn++){
      float4 w = ww4[nn][cc];
      acc[nn][0] += w.x*wv0.x + w.y*wv1.x + w.z*wv2.x + w.w*wv3.x;
      acc[nn][1] += w.x*wv0.y + w.y*wv1.y + w.z*wv2.y + w.w*wv3.y;
    }
  }
  #pragma unroll
  for(int nn=0;nn<16;nn++){
    unsigned pk = (unsigned)f2bf(acc[nn][0]) | ((unsigned)f2bf(acc[nn][1])<<16);
    *(unsigned*)&outp[nn*8] = pk;
  }
}

// ---------- GEMM A v8.1: v8 structure + MLP-fixed stage ----------
// g[r][n] = sum_v x[r][v]*M1[n][v]; M=8192 N=256 K=10016.
__global__ __launch_bounds__(512, 4) void k_gemm_a(const float* __restrict__ x,
    const unsigned short* __restrict__ M1f, float* __restrict__ gp, int nsplit){
  __shared__ unsigned short As[32768];   // 128 rows x 256 bf16 (swizzled 16B units)
  char* Ab = (char*)As;
  const int t = threadIdx.x;
  const int w = t>>6, lane = t&63;
  const int l15 = lane&15, sl = lane>>4;
  const int mh = w>>2, nq = w&3;
  const int r0 = blockIdx.x*128;
  const int kh = blockIdx.y;
  const int base = 313/nsplit, rem = 313%nsplit;
  const int c0 = kh*base + (kh<rem ? kh : rem);
  const int c1 = c0 + base + (kh<rem ? 1 : 0);

  const unsigned short* mbp[4];
  #pragma unroll
  for(int nt=0;nt<4;nt++)
    mbp[nt] = M1f + (size_t)(nq*4+nt)*313*512 + lane*8;

  f32x4 acc[4][4] = {};
  for(int cs=c0; cs<c1; cs+=8){
    const int cs_n = (c1-cs) < 8 ? (c1-cs) : 8;
    // ---- stage: wave w -> rows w*16..+15; lane covers floats lane*4..+3 ----
    if(lane*4 < cs_n*32){
      const int kk = cs*32 + lane*4;
      const bool ok = (kk + 4 <= 10000);   // 10000%4==0: fully valid or fully pad
      const int half8 = (lane&1)*8;
      const float* xp = x + (size_t)(r0 + w*16)*10000 + kk;
      #pragma unroll
      for(int g=0; g<2; g++){
        float4 rX[8];
        #pragma unroll
        for(int j=0;j<8;j++)
          rX[j] = ok ? *(const float4*)(xp + (size_t)(g*8+j)*10000)
                     : float4{0.f,0.f,0.f,0.f};
        #pragma unroll
        for(int j=0;j<8;j++){
          const int r = w*16 + g*8 + j;
          unsigned lo = (unsigned)f2bf(rX[j].x) | ((unsigned)f2bf(rX[j].y)<<16);
          unsigned hi = (unsigned)f2bf(rX[j].z) | ((unsigned)f2bf(rX[j].w)<<16);
          *(uint2*)(Ab + r*512 + (((lane>>1) ^ (r&7))<<4) + half8) = make_uint2(lo,hi);
        }
      }
    }
    __syncthreads();
    // ---- compute cs_n c-steps ----
    for(int cc=0; cc<cs_n; cc++){
      const int c = cs + cc;
      bf16x8 b[4];
      #pragma unroll
      for(int nt=0;nt<4;nt++)
        b[nt] = *(const bf16x8*)(mbp[nt] + (size_t)c*512);
      bf16x8 a[4];
      #pragma unroll
      for(int mt=0;mt<4;mt++){
        const int r = mh*64 + mt*16 + l15;
        const int p = (cc*4 + sl) ^ (l15&7);
        a[mt] = *(const bf16x8*)(Ab + r*512 + p*16);
      }
      #pragma unroll
      for(int mt=0;mt<4;mt++)
        #pragma unroll
        for(int nt=0;nt<4;nt++)
          acc[mt][nt] = __builtin_amdgcn_mfma_f32_16x16x32_bf16(a[mt], b[nt], acc[mt][nt], 0,0,0);
    }
    __syncthreads();
  }

  float* gout = gp + (size_t)kh*2097152;
  #pragma unroll
  for(int mt=0;mt<4;mt++)
    #pragma unroll
    for(int nt=0;nt<4;nt++)
      #pragma unroll
      for(int i2=0;i2<4;i2++){
        int row = r0 + mh*64 + mt*16 + sl*4 + i2;
        int col = nq*64 + nt*16 + l15;
        gout[(size_t)row*256 + col] = acc[mt][nt][i2];
      }
}

// ---------- reduce nsplit gp slices into slice 0 ----------
__global__ __launch_bounds__(256) void k_reduce(float* __restrict__ gp, int nsplit){
  size_t i = ((size_t)blockIdx.x*256 + threadIdx.x)*4;
  float4 acc = *(const float4*)(gp + i);
  for(int s=1;s<nsplit;s++){
    const float4 v = *(const float4*)(gp + (size_t)s*2097152 + i);
    acc.x+=v.x; acc.y+=v.y; acc.z+=v.z; acc.w+=v.w;
  }
  *(float4*)(gp + i) = acc;
}

// ---------- U-power chain, batched: U^{s+i} = U^s * U^i for i=1..s ----------
// Pf fp32 slots [p-2] for p=2..16; Pb bf16 slots likewise. U^1 = W_u / Wu_bf.
// 4 launches (s=1,2,4,8) replace the old 4 matsq; slot 14 = U^16 = A16.
__global__ __launch_bounds__(256) void k_pow(const float* __restrict__ Wu,
    float* __restrict__ Pf, unsigned short* __restrict__ Pb, int s){
  const int i = blockIdx.y + 1;                     // 1..s
  const float* A = (s==1) ? Wu : Pf + (size_t)(s-2)*65536;
  const float* B = (i==1) ? Wu : Pf + (size_t)(i-2)*65536;
  const int r = blockIdx.x, j = threadIdx.x;
  __shared__ float arow[256];
  arow[j] = A[r*256 + j];
  __syncthreads();
  float acc = 0.f;
  for(int k=0;k<256;k++) acc += arow[k]*B[k*256 + j];
  const size_t o = (size_t)(s+i-2)*65536 + r*256 + j;
  Pf[o] = acc;
  Pb[o] = f2bf(acc);
}

// ---------- A-fragment loader: row b = l15, k = kk*32 + sl*8 (+0..7), fp32->bf16 ----
__device__ __forceinline__ void load_afrag(const float* __restrict__ gs, bf16x8* a){
  #pragma unroll
  for(int kk=0;kk<8;kk++){
    float4 v0 = *(const float4*)(gs + kk*32);
    float4 v1 = *(const float4*)(gs + kk*32 + 4);
    u16x8 pk;
    pk[0]=f2bf(v0.x); pk[1]=f2bf(v0.y); pk[2]=f2bf(v0.z); pk[3]=f2bf(v0.w);
    pk[4]=f2bf(v1.x); pk[5]=f2bf(v1.y); pk[6]=f2bf(v1.z); pk[7]=f2bf(v1.w);
    a[kk] = __builtin_bit_cast(bf16x8, pk);
  }
}

// ---------- u_final[m] = sum_{k=0..15} g[m][k] @ (U^{15-k})^T  (parallel, zero-init scan tail)
// Replaces the 16-step serial k_scan_local. One block per chunk m; 4 waves = 256 cols.
__global__ __launch_bounds__(256) void k_ufinal(const float* __restrict__ g,
    const unsigned short* __restrict__ Wu_bf, const unsigned short* __restrict__ Pb,
    float* __restrict__ u_final){
  const int m = blockIdx.x;
  const int t = threadIdx.x, w = t>>6, lane = t&63, l15 = lane&15, sl = lane>>4;
  f32x4 acc[4] = {};
  for(int k=0;k<15;k++){
    bf16x8 a[8];
    load_afrag(g + ((size_t)l15*512 + m*16 + k)*256 + sl*8, a);
    const int p = 15-k;
    const unsigned short* Up = (p==1) ? Wu_bf : Pb + (size_t)(p-2)*65536;
    #pragma unroll
    for(int kk=0;kk<8;kk++)
      #pragma unroll
      for(int nt=0;nt<4;nt++){
        const int n = w*64 + nt*16 + l15;
        bf16x8 bv = *(const bf16x8*)&Up[(size_t)n*256 + kk*32 + sl*8];
        acc[nt] = __builtin_amdgcn_mfma_f32_16x16x32_bf16(a[kk], bv, acc[nt], 0,0,0);
      }
  }
  // k=15 term: U^0 = I -> direct add of g[m][15]
  #pragma unroll
  for(int nt=0;nt<4;nt++)
    #pragma unroll
    for(int i=0;i<4;i++){
      const int b = sl*4 + i, n = w*64 + nt*16 + l15;
      float v = acc[nt][i] + g[((size_t)b*512 + m*16 + 15)*256 + n];
      u_final[(size_t)m*4096 + b*256 + n] = v;
    }
}

// ---------- chunk-boundary scan: h_start[m][b][n], A16 = W_u^16 fp32 ----------
__global__ __launch_bounds__(1024) void k_chunk_scan(const float* __restrict__ hidden,
    const float* __restrict__ u_final, const float* __restrict__ A16,
    float* __restrict__ h_start){
  const int b = blockIdx.x;
  const int t = threadIdx.x;
  const int n = t & 255, q = t >> 8;     // q = k-split slice 0..3
  __shared__ float hc[256];
  __shared__ float part[3][256];
  float a[64];
  const float* ap = A16 + (size_t)n*256 + q*64;
  #pragma unroll
  for(int i=0;i<16;i++){
    float4 v = *(const float4*)(ap + i*4);
    a[i*4]=v.x; a[i*4+1]=v.y; a[i*4+2]=v.z; a[i*4+3]=v.w;
  }
  if(q==0){
    float h = hidden[b*256 + n];
    hc[n] = h;
    h_start[b*256 + n] = h;
  }
  __syncthreads();
  for(int m=1;m<32;m++){
    float acc0=0.f, acc1=0.f;
    #pragma unroll
    for(int i=0;i<64;i+=2){
      acc0 += a[i]  *hc[q*64 + i];
      acc1 += a[i+1]*hc[q*64 + i+1];
    }
    float acc = acc0 + acc1;
    if(q) part[q-1][n] = acc;
    __syncthreads();
    if(q==0){
      float v = acc + part[0][n] + part[1][n] + part[2][n]
              + u_final[(size_t)(m-1)*4096 + b*256 + n];
      hc[n] = v;
      h_start[(size_t)m*4096 + b*256 + n] = v;
    }
    __syncthreads();
  }
}

// ---------- h conv: h[m][j] = sum_{t<j} g[m][t]@(U^{j-t})^T + g[m][j] + h_start[m]@(U^{j+1})^T
// Replaces the 16-step serial k_scan_fix with 512 fully-parallel MFMA blocks.
// blockIdx.y -> j via (y<8 ? y : 23-y) so co-resident block pairs sum to equal work.
__global__ __launch_bounds__(256) void k_hconv(const float* __restrict__ g,
    const unsigned short* __restrict__ Wu_bf, const unsigned short* __restrict__ Pb,
    const float* __restrict__ h_start, unsigned short* __restrict__ h_bf){
  const int m = blockIdx.x;
  const int y = blockIdx.y;
  const int j = (y<8) ? y : 23-y;
  const int t = threadIdx.x, w = t>>6, lane = t&63, l15 = lane&15, sl = lane>>4;
  f32x4 acc[4] = {};
  for(int tt=0;tt<j;tt++){
    bf16x8 a[8];
    load_afrag(g + ((size_t)l15*512 + m*16 + tt)*256 + sl*8, a);
    const int p = j-tt;
    const unsigned short* Up = (p==1) ? Wu_bf : Pb + (size_t)(p-2)*65536;
    #pragma unroll
    for(int kk=0;kk<8;kk++)
      #pragma unroll
      for(int nt=0;nt<4;nt++){
        const int n = w*64 + nt*16 + l15;
        bf16x8 bv = *(const bf16x8*)&Up[(size_t)n*256 + kk*32 + sl*8];
        acc[nt] = __builtin_amdgcn_mfma_f32_16x16x32_bf16(a[kk], bv, acc[nt], 0,0,0);
      }
  }
  {  // h_start term, p = j+1
    bf16x8 a[8];
    load_afrag(h_start + (size_t)m*4096 + l15*256 + sl*8, a);
    const int p = j+1;
    const unsigned short* Up = (p==1) ? Wu_bf : Pb + (size_t)(p-2)*65536;
    #pragma unroll
    for(int kk=0;kk<8;kk++)
      #pragma unroll
      for(int nt=0;nt<4;nt++){
        const int n = w*64 + nt*16 + l15;
        bf16x8 bv = *(const bf16x8*)&Up[(size_t)n*256 + kk*32 + sl*8];
        acc[nt] = __builtin_amdgcn_mfma_f32_16x16x32_bf16(a[kk], bv, acc[nt], 0,0,0);
      }
  }
  // t=j term (U^0 = I): direct add of g[m][j]; write bf16 h
  #pragma unroll
  for(int nt=0;nt<4;nt++)
    #pragma unroll
    for(int i=0;i<4;i++){
      const int b = sl*4 + i, n = w*64 + nt*16 + l15;
      const size_t r = (size_t)b*512 + m*16 + j;
      float v = acc[nt][i] + g[r*256 + n];
      h_bf[r*256 + n] = f2bf(v);
    }
}

// ---------- GEMM C v2 (R8 verbatim): 128 rows x 256 v, grid (40,64), no swizzle ----
// No LDS: A-frags from L2-resident h_bf, B-frags contiguous from frag-major Wvf.
// Natural dispatch (vt fastest) keeps 8 vt-blocks co-writing one 128-row band:
// L2 merges the 32B partial-sector stores into full lines. Do NOT reorder.
__global__ __launch_bounds__(512, 4) void k_gemm_c(const unsigned short* __restrict__ h_bf,
    const unsigned short* __restrict__ Wvf, char* __restrict__ out){
  const int t = threadIdx.x;
  const int w = t>>6, lane = t&63;
  const int l15 = lane&15, sl = lane>>4;
  const int mh = w>>2, nq = w&3;
  const int vt = blockIdx.x, rg = blockIdx.y;
  const int rbase = rg*128 + mh*64;

  const unsigned short* bp[4];
  #pragma unroll
  for(int nt=0;nt<4;nt++)
    bp[nt] = Wvf + (size_t)(vt*16 + nq*4 + nt)*8*512 + lane*8;

  f32x4 acc[4][4] = {};
  #pragma unroll
  for(int kk=0;kk<8;kk++){
    bf16x8 b[4], a[4];
    #pragma unroll
    for(int nt=0;nt<4;nt++)
      b[nt] = *(const bf16x8*)(bp[nt] + (size_t)kk*512);
    #pragma unroll
    for(int mt=0;mt<4;mt++)
      a[mt] = *(const bf16x8*)&h_bf[(size_t)(rbase + mt*16 + l15)*256 + kk*32 + sl*8];
    #pragma unroll
    for(int mt=0;mt<4;mt++)
      #pragma unroll
      for(int nt=0;nt<4;nt++)
        acc[mt][nt] = __builtin_amdgcn_mfma_f32_16x16x32_bf16(a[mt], b[nt], acc[mt][nt], 0,0,0);
  }
  #pragma unroll
  for(int mt=0;mt<4;mt++)
    #pragma unroll
    for(int nt=0;nt<4;nt++){
      const int v = vt*256 + (nq*4+nt)*16 + l15;
      if(v < 10000){
        #pragma unroll
        for(int i=0;i<4;i++){
          int row = rbase + mt*16 + sl*4 + i;
          *(unsigned short*)(out + (size_t)row*40000 + (size_t)v*2) = f2bf(acc[mt][nt][i]);
        }
      }
    }
}

// ---------- per-row softmax in place: bf16 logits (first 20KB) -> fp32 probs (40KB) ----
// v2: 16B chunk loads (u16x8) + float4 stores; 10000 = 1250 chunks of 8, no tail.
__global__ __launch_bounds__(256) void k_softmax(char* __restrict__ out){
  const int r = blockIdx.x;
  const int t = threadIdx.x;
  const unsigned short* lg = (const unsigned short*)(out + (size_t)r*40000);
  float vals[40];
  float mx = -3.0e38f;
  #pragma unroll
  for(int j=0;j<5;j++){
    int c = j*256 + t;
    if(c < 1250){
      u16x8 p = *(const u16x8*)(lg + (size_t)c*8);
      #pragma unroll
      for(int q=0;q<8;q++){
        float a = bf2f(p[q]);
        vals[j*8+q] = a;
        mx = fmaxf(mx, a);
      }
    }
  }
  #pragma unroll
  for(int o=32;o>=1;o>>=1) mx = fmaxf(mx, __shfl_xor(mx, o));
  __shared__ float redm[4], reds[4];
  if((t&63)==0) redm[t>>6] = mx;
  __syncthreads();
  mx = fmaxf(fmaxf(redm[0],redm[1]), fmaxf(redm[2],redm[3]));
  float s = 0.f;
  #pragma unroll
  for(int j=0;j<5;j++){
    int c = j*256 + t;
    if(c < 1250){
      #pragma unroll
      for(int q=0;q<8;q++){
        float e = __expf(vals[j*8+q]-mx);
        vals[j*8+q] = e;
        s += e;
      }
    }
  }
  #pragma unroll
  for(int o=32;o>=1;o>>=1) s += __shfl_xor(s, o);
  if((t&63)==0) reds[t>>6] = s;
  __syncthreads();
  s = reds[0]+reds[1]+reds[2]+reds[3];
  float inv = 1.0f/s;
  float* op = (float*)(out + (size_t)r*40000);
  #pragma unroll
  for(int j=0;j<5;j++){
    int c = j*256 + t;
    if(c < 1250){
      float4 s0, s1;
      s0.x=vals[j*8+0]*inv; s0.y=vals[j*8+1]*inv; s0.z=vals[j*8+2]*inv; s0.w=vals[j*8+3]*inv;
      s1.x=vals[j*8+4]*inv; s1.y=vals[j*8+5]*inv; s1.z=vals[j*8+6]*inv; s1.w=vals[j*8+7]*inv;
      *(float4*)(op + (size_t)c*8)     = s0;
      *(float4*)(op + (size_t)c*8 + 4) = s1;
    }
  }
}

extern "C" void kernel_launch(void* const* d_in, const int* in_sizes, int n_in,
                              void* d_out, int out_size, void* d_ws, size_t ws_size,
                              hipStream_t stream){
  const float* x      = (const float*)d_in[0];
  const float* hidden = (const float*)d_in[1];
  const float* W_emb  = (const float*)d_in[2];
  const float* W_w    = (const float*)d_in[3];
  const float* W_u    = (const float*)d_in[4];
  const float* W_v    = (const float*)d_in[5];

  // pick K-split degree by available workspace (deterministic: ws_size is fixed)
  const size_t fixed_bytes = 16269312;  // keep thresholds identical to the proven run
  int nsplit = 2;
  if(ws_size >= (size_t)8*2097152*4 + fixed_bytes) nsplit = 8;
  else if(ws_size >= (size_t)4*2097152*4 + fixed_bytes) nsplit = 4;

  char* w = (char*)d_ws;
  size_t off = (size_t)nsplit * 2097152 * 4;
  float*          gp      = (float*)(w + 0);
  unsigned short* M1f     = (unsigned short*)(w + off);          off += 5128192;
  unsigned short* Wvf     = (unsigned short*)(w + off);          off += 5242880;
  unsigned short* Wu_bf   = (unsigned short*)(w + off);          off += 131072;
  float*          u_final = (float*)(w + off);                   off += 524288;
  float*          h_start = (float*)(w + off);                   off += 524288;
  unsigned short* h_bf    = (unsigned short*)(w + off);          off += 4194304;

  // U-power storage lives in gp slice 1 (dead after k_reduce; nsplit>=2 always):
  // Pf: 15 fp32 256x256 slices (U^2..U^16), Pb: 15 bf16 slices. 5.9 MB <= 8.4 MB.
  float*          Pf = gp + 2097152;
  unsigned short* Pb = (unsigned short*)(Pf + 15*65536);

  k_m1<<<dim3(20,16),256,0,stream>>>(W_w, W_emb, M1f);
  k_gemm_a<<<dim3(64,nsplit),512,0,stream>>>(x, M1f, gp, nsplit);
  k_wvf<<<224,256,0,stream>>>(W_v, Wvf, W_u, Wu_bf);
  k_reduce<<<2048,256,0,stream>>>(gp, nsplit);
  k_pow<<<dim3(256,1),256,0,stream>>>(W_u, Pf, Pb, 1);   // U^2
  k_pow<<<dim3(256,2),256,0,stream>>>(W_u, Pf, Pb, 2);   // U^3,U^4
  k_pow<<<dim3(256,4),256,0,stream>>>(W_u, Pf, Pb, 4);   // U^5..U^8
  k_pow<<<dim3(256,8),256,0,stream>>>(W_u, Pf, Pb, 8);   // U^9..U^16
  k_ufinal<<<32,256,0,stream>>>(gp, Wu_bf, Pb, u_final);
  k_chunk_scan<<<16,1024,0,stream>>>(hidden, u_final, Pf + 14*65536, h_start);
  k_hconv<<<dim3(32,16),256,0,stream>>>(gp, Wu_bf, Pb, h_start, h_bf);
  k_gemm_c<<<dim3(40,64),512,0,stream>>>(h_bf, Wvf, (char*)d_out);
  k_softmax<<<8192,256,0,stream>>>((char*)d_out);
}

// Round 2
// 509.405 us; speedup vs baseline: 1.3223x; 1.3223x over previous
//
#include <hip/hip_runtime.h>

typedef __bf16 bf16x8 __attribute__((ext_vector_type(8)));
typedef float f32x4 __attribute__((ext_vector_type(4)));
typedef unsigned short u16x8 __attribute__((ext_vector_type(8)));

#define VP 10016  // 10000 padded to multiple of 32 (313 c-steps of 32)

__device__ __forceinline__ unsigned short f2bf(float x){
  unsigned u = __builtin_bit_cast(unsigned, x);
  u += 0x7fffu + ((u>>16)&1u);
  return (unsigned short)(u>>16);
}
__device__ __forceinline__ float bf2f(unsigned short h){
  unsigned u = ((unsigned)h)<<16;
  return __builtin_bit_cast(float, u);
}

// ---------- Wvf: fragment-major W_v  Wvf[vg 640][kk 8][lane 64][8 bf16] ----------
// blocks 160..223 cast W_u -> bf16 (64 blocks x 256 thr x 1 float4 = 65536 floats).
__global__ __launch_bounds__(256) void k_wvf(const float* __restrict__ W_v,
                                             unsigned short* __restrict__ Wvf,
                                             const float* __restrict__ W_u,
                                             unsigned short* __restrict__ Wu_bf){
  if(blockIdx.x >= 160){
    int i = (blockIdx.x-160)*256 + threadIdx.x;   // 0..16383 float4-groups
    const float4 v = *(const float4*)(W_u + (size_t)i*4);
    unsigned a = (unsigned)f2bf(v.x) | ((unsigned)f2bf(v.y)<<16);
    unsigned b = (unsigned)f2bf(v.z) | ((unsigned)f2bf(v.w)<<16);
    *(uint2*)(Wu_bf + (size_t)i*4) = make_uint2(a,b);
    return;
  }
  const int t = threadIdx.x;
  const int w = t>>6, lane = t&63;
  const int l15 = lane&15, sl = lane>>4;
  const int vg = blockIdx.x*4 + w;      // 0..639
  const int v = vg*16 + l15;
  #pragma unroll
  for(int kk=0;kk<8;kk++){
    u16x8 pk = {0,0,0,0,0,0,0,0};
    if(v < 10000){
      const float* p = W_v + (size_t)v*256 + kk*32 + sl*8;
      float4 v0 = *(const float4*)p;
      float4 v1 = *(const float4*)(p+4);
      pk[0]=f2bf(v0.x); pk[1]=f2bf(v0.y); pk[2]=f2bf(v0.z); pk[3]=f2bf(v0.w);
      pk[4]=f2bf(v1.x); pk[5]=f2bf(v1.y); pk[6]=f2bf(v1.z); pk[7]=f2bf(v1.w);
    }
    *(u16x8*)(Wvf + ((size_t)vg*8 + kk)*512 + lane*8) = pk;
  }
}

// ---------- M1f: fragment-major  M1f[ngrp 16][c 313][lane 64][8 bf16] ----------
__global__ __launch_bounds__(256) void k_m1(const float* __restrict__ W_w,
                                            const float* __restrict__ W_emb,
                                            unsigned short* __restrict__ M1f){
  __shared__ float4 ww4[16][75];   // [n][c4] covers e = 4c4..4c4+3  (300 = 75*4)
  const int t = threadIdx.x;
  const int ngrp = blockIdx.y;
  const int n0 = ngrp*16;
  for(int i=t; i<16*75; i+=256){
    int n = i/75, c = i - n*75;
    ww4[n][c] = *(const float4*)(W_w + (size_t)(n0+n)*300 + c*4);
  }
  __syncthreads();
  const int v0 = blockIdx.x*512 + t*2;
  if(v0 >= VP) return;
  const int c  = v0>>5;
  const int sl = (v0>>3)&3;
  const int j  = v0&7;          // even
  unsigned short* outp = M1f + (size_t)(ngrp*313 + c)*512 + sl*128 + j;
  if(v0 >= 10000){
    #pragma unroll
    for(int nn=0;nn<16;nn++) *(unsigned*)&outp[nn*8] = 0u;
    return;
  }
  float acc[16][2];
  #pragma unroll
  for(int nn=0;nn<16;nn++){ acc[nn][0]=0.f; acc[nn][1]=0.f; }
  #pragma unroll 2
  for(int cc=0;cc<75;cc++){
    const float* eb = W_emb + (size_t)(4*cc)*10000 + v0;
    float2 wv0 = *(const float2*)(eb);
    float2 wv1 = *(const float2*)(eb + 10000);
    float2 wv2 = *(const float2*)(eb + 20000);
    float2 wv3 = *(const float2*)(eb + 30000);
    #pragma unroll
    for(int nn=0;nn<16;nn++){
      float4 w = ww4[nn][cc];
      acc[nn][0] += w.x*wv0.x + w.y*wv1.x + w.z*wv2.x + w.w*wv3.x;
      acc[nn][1] += w.x*wv0.y + w.y*wv1.y + w.z*wv2.y + w.w*wv3.y;
    }
  }
  #pragma unroll
  for(int nn=0;nn<16;nn++){
    unsigned pk = (unsigned)f2bf(acc[nn][0]) | ((unsigned)f2bf(acc[nn][1])<<16);
    *(unsigned*)&outp[nn*8] = pk;
  }
}

// ---------- GEMM A v8.1: v8 structure + MLP-fixed stage ----------
// g[r][n] = sum_v x[r][v]*M1[n][v]; M=8192 N=256 K=10016.
__global__ __launch_bounds__(512, 4) void k_gemm_a(const float* __restrict__ x,
    const unsigned short* __restrict__ M1f, float* __restrict__ gp, int nsplit){
  __shared__ unsigned short As[32768];   // 128 rows x 256 bf16 (swizzled 16B units)
  char* Ab = (char*)As;
  const int t = threadIdx.x;
  const int w = t>>6, lane = t&63;
  const int l15 = lane&15, sl = lane>>4;
  const int mh = w>>2, nq = w&3;
  const int r0 = blockIdx.x*128;
  const int kh = blockIdx.y;
  const int base = 313/nsplit, rem = 313%nsplit;
  const int c0 = kh*base + (kh<rem ? kh : rem);
  const int c1 = c0 + base + (kh<rem ? 1 : 0);

  const unsigned short* mbp[4];
  #pragma unroll
  for(int nt=0;nt<4;nt++)
    mbp[nt] = M1f + (size_t)(nq*4+nt)*313*512 + lane*8;

  f32x4 acc[4][4] = {};
  for(int cs=c0; cs<c1; cs+=8){
    const int cs_n = (c1-cs) < 8 ? (c1-cs) : 8;
    // ---- stage: wave w -> rows w*16..+15; lane covers floats lane*4..+3 ----
    if(lane*4 < cs_n*32){
      const int kk = cs*32 + lane*4;
      const bool ok = (kk + 4 <= 10000);   // 10000%4==0: fully valid or fully pad
      const int unit0 = lane>>1;
      const int half8 = (lane&1)*8;
      const float* xp = x + (size_t)(r0 + w*16)*10000 + kk;
      #pragma unroll
      for(int g=0; g<2; g++){
        float4 rX[8];
        #pragma unroll
        for(int j=0;j<8;j++)
          rX[j] = ok ? *(const float4*)(xp + (size_t)(g*8+j)*10000)
                     : float4{0.f,0.f,0.f,0.f};
        #pragma unroll
        for(int j=0;j<8;j++){
          const int r = w*16 + g*8 + j;
          unsigned lo = (unsigned)f2bf(rX[j].x) | ((unsigned)f2bf(rX[j].y)<<16);
          unsigned hi = (unsigned)f2bf(rX[j].z) | ((unsigned)f2bf(rX[j].w)<<16);
          *(uint2*)(Ab + r*512 + (((lane>>1) ^ (r&7))<<4) + half8) = make_uint2(lo,hi);
        }
      }
      (void)unit0;
    }
    __syncthreads();
    // ---- compute cs_n c-steps ----
    for(int cc=0; cc<cs_n; cc++){
      const int c = cs + cc;
      bf16x8 b[4];
      #pragma unroll
      for(int nt=0;nt<4;nt++)
        b[nt] = *(const bf16x8*)(mbp[nt] + (size_t)c*512);
      bf16x8 a[4];
      #pragma unroll
      for(int mt=0;mt<4;mt++){
        const int r = mh*64 + mt*16 + l15;
        const int p = (cc*4 + sl) ^ (l15&7);
        a[mt] = *(const bf16x8*)(Ab + r*512 + p*16);
      }
      #pragma unroll
      for(int mt=0;mt<4;mt++)
        #pragma unroll
        for(int nt=0;nt<4;nt++)
          acc[mt][nt] = __builtin_amdgcn_mfma_f32_16x16x32_bf16(a[mt], b[nt], acc[mt][nt], 0,0,0);
    }
    __syncthreads();
  }

  float* gout = gp + (size_t)kh*2097152;
  #pragma unroll
  for(int mt=0;mt<4;mt++)
    #pragma unroll
    for(int nt=0;nt<4;nt++)
      #pragma unroll
      for(int i2=0;i2<4;i2++){
        int row = r0 + mh*64 + mt*16 + sl*4 + i2;
        int col = nq*64 + nt*16 + l15;
        gout[(size_t)row*256 + col] = acc[mt][nt][i2];
      }
}

// ---------- reduce nsplit gp slices into slice 0 ----------
__global__ __launch_bounds__(256) void k_reduce(float* __restrict__ gp, int nsplit){
  size_t i = ((size_t)blockIdx.x*256 + threadIdx.x)*4;
  float4 acc = *(const float4*)(gp + i);
  for(int s=1;s<nsplit;s++){
    const float4 v = *(const float4*)(gp + (size_t)s*2097152 + i);
    acc.x+=v.x; acc.y+=v.y; acc.z+=v.z; acc.w+=v.w;
  }
  *(float4*)(gp + i) = acc;
}

// ---------- 256x256 fp32 matrix multiply (for W_u powers) ----------
__global__ __launch_bounds__(256) void k_matsq(const float* __restrict__ A,
    const float* __restrict__ B, float* __restrict__ C){
  int i = blockIdx.x, j = threadIdx.x;
  __shared__ float arow[256];
  arow[j] = A[i*256 + j];
  __syncthreads();
  float acc = 0.f;
  for(int k=0;k<256;k++) acc += arow[k]*B[k*256 + j];
  C[i*256 + j] = acc;
}

// ---------- local scan per chunk (zero init): u_final[m][b][n] ----------
__global__ __launch_bounds__(256) void k_scan_local(const float* __restrict__ g,
    const unsigned short* __restrict__ Wu, float* __restrict__ u_final){
  __shared__ unsigned short ub[2][16*256];
  const int m = blockIdx.x;
  const int t = threadIdx.x, wave=t>>6, lane=t&63, l15=lane&15, sl=lane>>4;
  for(int i=t;i<2048;i+=256) ((unsigned*)ub[0])[i] = 0u;
  __syncthreads();
  int buf = 0;
  for(int j=0;j<16;j++){
    float gv[4][4];
    #pragma unroll
    for(int nt=0;nt<4;nt++)
      #pragma unroll
      for(int i=0;i<4;i++){
        int b = sl*4 + i;
        int n = wave*64 + nt*16 + l15;
        size_t r = (size_t)b*512 + m*16 + j;
        gv[nt][i] = g[r*256 + n];
      }
    bf16x8 af[8];
    #pragma unroll
    for(int kk=0;kk<8;kk++){
      int slot = kk*4 + sl;
      af[kk] = *(const bf16x8*)&ub[buf][l15*256 + ((slot ^ (l15&7))<<3)];
    }
    f32x4 acc[4] = {};
    #pragma unroll
    for(int kk=0;kk<8;kk++)
      #pragma unroll
      for(int nt=0;nt<4;nt++){
        int n = wave*64 + nt*16 + l15;
        bf16x8 bv = *(const bf16x8*)&Wu[(size_t)n*256 + kk*32 + sl*8];
        acc[nt] = __builtin_amdgcn_mfma_f32_16x16x32_bf16(af[kk], bv, acc[nt], 0,0,0);
      }
    #pragma unroll
    for(int nt=0;nt<4;nt++)
      #pragma unroll
      for(int i=0;i<4;i++){
        int b = sl*4 + i;
        int n = wave*64 + nt*16 + l15;
        float v = acc[nt][i] + gv[nt][i];
        ub[buf^1][b*256 + (((n>>3) ^ (b&7))<<3) + (n&7)] = f2bf(v);
        if(j==15) u_final[m*4096 + b*256 + n] = v;
      }
    __syncthreads();
    buf ^= 1;
  }
}

// ---------- chunk-boundary scan: h_start[m][b][n], A16 = W_u^16 fp32 ----------
__global__ __launch_bounds__(1024) void k_chunk_scan(const float* __restrict__ hidden,
    const float* __restrict__ u_final, const float* __restrict__ A16,
    float* __restrict__ h_start){
  const int b = blockIdx.x;
  const int t = threadIdx.x;
  const int n = t & 255, q = t >> 8;     // q = k-split slice 0..3
  __shared__ float hc[256];
  __shared__ float part[3][256];
  float a[64];
  const float* ap = A16 + (size_t)n*256 + q*64;
  #pragma unroll
  for(int i=0;i<16;i++){
    float4 v = *(const float4*)(ap + i*4);
    a[i*4]=v.x; a[i*4+1]=v.y; a[i*4+2]=v.z; a[i*4+3]=v.w;
  }
  if(q==0){
    float h = hidden[b*256 + n];
    hc[n] = h;
    h_start[b*256 + n] = h;
  }
  __syncthreads();
  for(int m=1;m<32;m++){
    float acc0=0.f, acc1=0.f;
    #pragma unroll
    for(int i=0;i<64;i+=2){
      acc0 += a[i]  *hc[q*64 + i];
      acc1 += a[i+1]*hc[q*64 + i+1];
    }
    float acc = acc0 + acc1;
    if(q) part[q-1][n] = acc;
    __syncthreads();
    if(q==0){
      float v = acc + part[0][n] + part[1][n] + part[2][n]
              + u_final[(size_t)(m-1)*4096 + b*256 + n];
      hc[n] = v;
      h_start[(size_t)m*4096 + b*256 + n] = v;
    }
    __syncthreads();
  }
}

// ---------- rerun chunks from true init, emit h_bf[r][n] bf16 ----------
__global__ __launch_bounds__(256) void k_scan_fix(const float* __restrict__ g,
    const unsigned short* __restrict__ Wu, const float* __restrict__ h_start,
    unsigned short* __restrict__ h_bf){
  __shared__ unsigned short ub[2][16*256];
  const int m = blockIdx.x;
  const int t=threadIdx.x, wave=t>>6, lane=t&63, l15=lane&15, sl=lane>>4;
  for(int u=t; u<512; u+=256){
    int b = u>>5, s = u&31;
    const float* hp = h_start + m*4096 + b*256 + s*8;
    float4 v0 = *(const float4*)hp;
    float4 v1 = *(const float4*)(hp+4);
    u16x8 pk;
    pk[0]=f2bf(v0.x); pk[1]=f2bf(v0.y); pk[2]=f2bf(v0.z); pk[3]=f2bf(v0.w);
    pk[4]=f2bf(v1.x); pk[5]=f2bf(v1.y); pk[6]=f2bf(v1.z); pk[7]=f2bf(v1.w);
    *(u16x8*)&ub[0][b*256 + ((s ^ (b&7))<<3)] = pk;
  }
  __syncthreads();
  int buf = 0;
  for(int j=0;j<16;j++){
    float gv[4][4];
    #pragma unroll
    for(int nt=0;nt<4;nt++)
      #pragma unroll
      for(int i=0;i<4;i++){
        int b = sl*4 + i;
        int n = wave*64 + nt*16 + l15;
        size_t r = (size_t)b*512 + m*16 + j;
        gv[nt][i] = g[r*256 + n];
      }
    bf16x8 af[8];
    #pragma unroll
    for(int kk=0;kk<8;kk++){
      int slot = kk*4 + sl;
      af[kk] = *(const bf16x8*)&ub[buf][l15*256 + ((slot ^ (l15&7))<<3)];
    }
    f32x4 acc[4] = {};
    #pragma unroll
    for(int kk=0;kk<8;kk++)
      #pragma unroll
      for(int nt=0;nt<4;nt++){
        int n = wave*64 + nt*16 + l15;
        bf16x8 bv = *(const bf16x8*)&Wu[(size_t)n*256 + kk*32 + sl*8];
        acc[nt] = __builtin_amdgcn_mfma_f32_16x16x32_bf16(af[kk], bv, acc[nt], 0,0,0);
      }
    #pragma unroll
    for(int nt=0;nt<4;nt++)
      #pragma unroll
      for(int i=0;i<4;i++){
        int b = sl*4 + i;
        int n = wave*64 + nt*16 + l15;
        float v = acc[nt][i] + gv[nt][i];
        unsigned short hb = f2bf(v);
        ub[buf^1][b*256 + (((n>>3) ^ (b&7))<<3) + (n&7)] = hb;
        size_t r = (size_t)b*512 + m*16 + j;
        h_bf[r*256 + n] = hb;
      }
    __syncthreads();
    buf ^= 1;
  }
}

// ---------- GEMM C v3: band-pair. grid (40,32), vt fastest (DO NOT reorder). ----
// Each block holds all 32 B-frags (ball[8][4], 128 VGPR) in registers and computes
// TWO 128-row bands (rg = y and y+32), halving the ~656 MB Wvf L3 re-stream to
// ~328 MB. Store pattern per band unchanged: 40 vt-blocks co-write each band so
// L2 merges the 32B partial-sector stores. Numerics identical to v2 (same MFMA
// order per output). launch_bounds(512,2): VGPR cap 256, 1 block/CU.
__global__ __launch_bounds__(512, 2) void k_gemm_c(const unsigned short* __restrict__ h_bf,
    const unsigned short* __restrict__ Wvf, char* __restrict__ out){
  const int t = threadIdx.x;
  const int w = t>>6, lane = t&63;
  const int l15 = lane&15, sl = lane>>4;
  const int mh = w>>2, nq = w&3;
  const int vt = blockIdx.x;

  const unsigned short* bp[4];
  #pragma unroll
  for(int nt=0;nt<4;nt++)
    bp[nt] = Wvf + (size_t)(vt*16 + nq*4 + nt)*8*512 + lane*8;

  bf16x8 ball[8][4];
  #pragma unroll
  for(int kk=0;kk<8;kk++)
    #pragma unroll
    for(int nt=0;nt<4;nt++)
      ball[kk][nt] = *(const bf16x8*)(bp[nt] + (size_t)kk*512);

  #pragma unroll
  for(int band=0; band<2; band++){
    const int rg = blockIdx.y + band*32;
    const int rbase = rg*128 + mh*64;
    f32x4 acc[4][4] = {};
    #pragma unroll
    for(int kk=0;kk<8;kk++){
      bf16x8 a[4];
      #pragma unroll
      for(int mt=0;mt<4;mt++)
        a[mt] = *(const bf16x8*)&h_bf[(size_t)(rbase + mt*16 + l15)*256 + kk*32 + sl*8];
      #pragma unroll
      for(int mt=0;mt<4;mt++)
        #pragma unroll
        for(int nt=0;nt<4;nt++)
          acc[mt][nt] = __builtin_amdgcn_mfma_f32_16x16x32_bf16(a[mt], ball[kk][nt], acc[mt][nt], 0,0,0);
    }
    #pragma unroll
    for(int mt=0;mt<4;mt++)
      #pragma unroll
      for(int nt=0;nt<4;nt++){
        const int v = vt*256 + (nq*4+nt)*16 + l15;
        if(v < 10000){
          #pragma unroll
          for(int i=0;i<4;i++){
            int row = rbase + mt*16 + sl*4 + i;
            *(unsigned short*)(out + (size_t)row*40000 + (size_t)v*2) = f2bf(acc[mt][nt][i]);
          }
        }
      }
  }
}

// ---------- per-row softmax in place: bf16 logits (first 20KB) -> fp32 probs (40KB) ----
// v2: 16B chunk loads (u16x8) + float4 stores; 10000 = 1250 chunks of 8, no tail.
__global__ __launch_bounds__(256) void k_softmax(char* __restrict__ out){
  const int r = blockIdx.x;
  const int t = threadIdx.x;
  const unsigned short* lg = (const unsigned short*)(out + (size_t)r*40000);
  float vals[40];
  float mx = -3.0e38f;
  #pragma unroll
  for(int j=0;j<5;j++){
    int c = j*256 + t;
    if(c < 1250){
      u16x8 p = *(const u16x8*)(lg + (size_t)c*8);
      #pragma unroll
      for(int q=0;q<8;q++){
        float a = bf2f(p[q]);
        vals[j*8+q] = a;
        mx = fmaxf(mx, a);
      }
    }
  }
  #pragma unroll
  for(int o=32;o>=1;o>>=1) mx = fmaxf(mx, __shfl_xor(mx, o));
  __shared__ float redm[4], reds[4];
  if((t&63)==0) redm[t>>6] = mx;
  __syncthreads();
  mx = fmaxf(fmaxf(redm[0],redm[1]), fmaxf(redm[2],redm[3]));
  float s = 0.f;
  #pragma unroll
  for(int j=0;j<5;j++){
    int c = j*256 + t;
    if(c < 1250){
      #pragma unroll
      for(int q=0;q<8;q++){
        float e = __expf(vals[j*8+q]-mx);
        vals[j*8+q] = e;
        s += e;
      }
    }
  }
  #pragma unroll
  for(int o=32;o>=1;o>>=1) s += __shfl_xor(s, o);
  if((t&63)==0) reds[t>>6] = s;
  __syncthreads();
  s = reds[0]+reds[1]+reds[2]+reds[3];
  float inv = 1.0f/s;
  float* op = (float*)(out + (size_t)r*40000);
  #pragma unroll
  for(int j=0;j<5;j++){
    int c = j*256 + t;
    if(c < 1250){
      float4 s0, s1;
      s0.x=vals[j*8+0]*inv; s0.y=vals[j*8+1]*inv; s0.z=vals[j*8+2]*inv; s0.w=vals[j*8+3]*inv;
      s1.x=vals[j*8+4]*inv; s1.y=vals[j*8+5]*inv; s1.z=vals[j*8+6]*inv; s1.w=vals[j*8+7]*inv;
      *(float4*)(op + (size_t)c*8)     = s0;
      *(float4*)(op + (size_t)c*8 + 4) = s1;
    }
  }
}

extern "C" void kernel_launch(void* const* d_in, const int* in_sizes, int n_in,
                              void* d_out, int out_size, void* d_ws, size_t ws_size,
                              hipStream_t stream){
  const float* x      = (const float*)d_in[0];
  const float* hidden = (const float*)d_in[1];
  const float* W_emb  = (const float*)d_in[2];
  const float* W_w    = (const float*)d_in[3];
  const float* W_u    = (const float*)d_in[4];
  const float* W_v    = (const float*)d_in[5];

  // pick K-split degree by available workspace (deterministic: ws_size is fixed)
  const size_t fixed_bytes = 16269312;  // all non-gp buffers
  int nsplit = 2;
  if(ws_size >= (size_t)8*2097152*4 + fixed_bytes) nsplit = 8;
  else if(ws_size >= (size_t)4*2097152*4 + fixed_bytes) nsplit = 4;

  char* w = (char*)d_ws;
  size_t off = (size_t)nsplit * 2097152 * 4;
  float*          gp      = (float*)(w + 0);
  unsigned short* M1f     = (unsigned short*)(w + off);          off += 5128192;
  unsigned short* Wvf     = (unsigned short*)(w + off);          off += 5242880;
  unsigned short* Wu_bf   = (unsigned short*)(w + off);          off += 131072;
  float*          u_final = (float*)(w + off);                   off += 524288;
  float*          h_start = (float*)(w + off);                   off += 524288;
  unsigned short* h_bf    = (unsigned short*)(w + off);          off += 4194304;
  float*          powA    = (float*)(w + off);                   off += 262144;
  float*          powB    = (float*)(w + off);                   off += 262144;

  k_m1<<<dim3(20,16),256,0,stream>>>(W_w, W_emb, M1f);
  k_gemm_a<<<dim3(64,nsplit),512,0,stream>>>(x, M1f, gp, nsplit);
  k_wvf<<<224,256,0,stream>>>(W_v, Wvf, W_u, Wu_bf);
  k_matsq<<<256,256,0,stream>>>(W_u,  W_u,  powA);   // W_u^2
  k_matsq<<<256,256,0,stream>>>(powA, powA, powB);   // W_u^4
  k_matsq<<<256,256,0,stream>>>(powB, powB, powA);   // W_u^8
  k_matsq<<<256,256,0,stream>>>(powA, powA, powB);   // W_u^16
  k_reduce<<<2048,256,0,stream>>>(gp, nsplit);
  k_scan_local<<<32,256,0,stream>>>(gp, Wu_bf, u_final);
  k_chunk_scan<<<16,1024,0,stream>>>(hidden, u_final, powB, h_start);
  k_scan_fix<<<32,256,0,stream>>>(gp, Wu_bf, h_start, h_bf);
  k_gemm_c<<<dim3(40,32),512,0,stream>>>(h_bf, Wvf, (char*)d_out);
  k_softmax<<<8192,256,0,stream>>>((char*)d_out);
}